// Round 16
// baseline (247.157 us; speedup 1.0000x reference)
//
#include <hip/hip_runtime.h>
#include <hip/hip_bf16.h>
#include <math.h>

#define NTOT  8192
#define DIM   512
#define BATCH (NTOT/2)
#define TEMP_INV 5.0f   // 1/0.2
#define TTILE 64                      // 8192 / 128 tiles per side
#define NBLK  (TTILE*(TTILE+1)/2)     // 2080 upper-triangle tiles

typedef __attribute__((ext_vector_type(8))) short bf16x8;
typedef __attribute__((ext_vector_type(4))) float f32x4;

__device__ __forceinline__ float b2f(unsigned short u)
{
    unsigned int x = (unsigned int)u << 16;
    float f; __builtin_memcpy(&f, &x, 4); return f;
}

// column-major triangle decode: t = bj*(bj+1)/2 + bi, bi <= bj.
__device__ __forceinline__ void decode_tile(int t, int& bi, int& bj)
{
    int b = (int)((sqrtf(8.0f * (float)t + 1.0f) - 1.0f) * 0.5f);
    while ((b + 1) * (b + 2) / 2 <= t) ++b;
    while (b * (b + 1) / 2 > t)       --b;
    bj = b;
    bi = t - b * (b + 1) / 2;
}

__device__ __forceinline__ unsigned int pack_bf16_2(float a, float b)
{
    __hip_bfloat16 ha = __float2bfloat16(a), hb = __float2bfloat16(b);
    unsigned short ua, ub;
    __builtin_memcpy(&ua, &ha, 2); __builtin_memcpy(&ub, &hb, 2);
    return (unsigned int)ua | ((unsigned int)ub << 16);
}

// ---------------- normalize: one wave per row ----------------
__global__ __launch_bounds__(256)
void normalize_k(const float* __restrict__ z, __hip_bfloat16* __restrict__ zn)
{
    const int lane = threadIdx.x & 63, wave = threadIdx.x >> 6;
    const int row  = blockIdx.x * 4 + wave;
    const float4* zr = (const float4*)(z + (size_t)row * DIM);
    const float4 a = zr[lane];
    const float4 b = zr[lane + 64];
    float ss = a.x*a.x + a.y*a.y + a.z*a.z + a.w*a.w
             + b.x*b.x + b.y*b.y + b.z*b.z + b.w*b.w;
    #pragma unroll
    for (int off = 1; off < 64; off <<= 1) ss += __shfl_xor(ss, off);
    const float inv = 1.0f / fmaxf(sqrtf(ss), 1e-12f);
    uint2* zo = (uint2*)(zn + (size_t)row * DIM);
    uint2 o0, o1;
    o0.x = pack_bf16_2(a.x * inv, a.y * inv);
    o0.y = pack_bf16_2(a.z * inv, a.w * inv);
    o1.x = pack_bf16_2(b.x * inv, b.y * inv);
    o1.y = pack_bf16_2(b.z * inv, b.w * inv);
    zo[lane]      = o0;
    zo[lane + 64] = o1;
}

// ---------------- shared MFMA K-loop: 128x128 tile, BK=32, 2-stage ring ----------------
__device__ __forceinline__ void issue4(const __hip_bfloat16* A, int sA,
                                       const __hip_bfloat16* B, int sB,
                                       int gk, unsigned short* Ad, unsigned short* Bd,
                                       int wave, int lane)
{
    const int f_l = lane & 15, q_l = lane >> 4;
    #pragma unroll
    for (int q = 0; q < 2; ++q) {
        const int s = wave * 2 + q;
        const __hip_bfloat16* ga = A + (size_t)(s * 16 + f_l) * sA + gk + q_l * 8;
        const __hip_bfloat16* gb = B + (size_t)(s * 16 + f_l) * sB + gk + q_l * 8;
        __builtin_amdgcn_global_load_lds(
            (const __attribute__((address_space(1))) unsigned int*)ga,
            (__attribute__((address_space(3))) unsigned int*)(Ad + s * 512 + lane * 8),
            16, 0, 0);
        __builtin_amdgcn_global_load_lds(
            (const __attribute__((address_space(1))) unsigned int*)gb,
            (__attribute__((address_space(3))) unsigned int*)(Bd + s * 512 + lane * 8),
            16, 0, 0);
    }
}

// 2-stage ring, depth-2 prefetch, counted vmcnt. Safety: buf[ki&1] is re-targeted
// (for tile ki+2) only after barrier2, which every wave reaches with its ds_reads
// of buf[ki&1] complete (explicit lgkmcnt(0)); so block-wide reads-before-overwrite.
template<int NSTEP>
__device__ __forceinline__ void mm_kloop(const __hip_bfloat16* A, int sA,
                                         const __hip_bfloat16* B, int sB,
                                         unsigned short (*As)[4096],
                                         unsigned short (*Bs)[4096],
                                         f32x4 acc[4][4], int wave, int lane)
{
    const int wr = wave >> 1, wc = wave & 1;
    issue4(A, sA, B, sB, 0,  As[0], Bs[0], wave, lane);
    issue4(A, sA, B, sB, 32, As[1], Bs[1], wave, lane);
    #pragma unroll
    for (int ki = 0; ki < NSTEP; ++ki) {
        // buf[ki&1]'s 4 loads are the oldest outstanding; tile ki+1's 4 stay in flight.
        if (ki < NSTEP - 1) asm volatile("s_waitcnt vmcnt(4)\n\ts_barrier" ::: "memory");
        else                asm volatile("s_waitcnt vmcnt(0)\n\ts_barrier" ::: "memory");
        __builtin_amdgcn_sched_barrier(0);
        const unsigned short* Ap = As[ki & 1];
        const unsigned short* Bp = Bs[ki & 1];
        bf16x8 af[4], bfr[4];
        #pragma unroll
        for (int r = 0; r < 4; ++r)
            af[r] = *(const bf16x8*)(Ap + (wr * 4 + r) * 512 + lane * 8);
        #pragma unroll
        for (int c = 0; c < 4; ++c)
            bfr[c] = *(const bf16x8*)(Bp + (wc * 4 + c) * 512 + lane * 8);
        #pragma unroll
        for (int r = 0; r < 4; ++r)
            #pragma unroll
            for (int c = 0; c < 4; ++c)
                acc[r][c] = __builtin_amdgcn_mfma_f32_16x16x32_bf16(af[r], bfr[c], acc[r][c], 0, 0, 0);
        if (ki + 2 < NSTEP) {
            // all my ds_reads of buf[ki&1] complete; sync block; then re-target it.
            __builtin_amdgcn_sched_barrier(0);
            asm volatile("s_waitcnt lgkmcnt(0)\n\ts_barrier" ::: "memory");
            __builtin_amdgcn_sched_barrier(0);
            issue4(A, sA, B, sB, (ki + 2) * 32, As[ki & 1], Bs[ki & 1], wave, lane);
        }
    }
}

// ---------------- pass 1: triangle GEMM + stats epilogue (rowsum/rowsumsq atomics) ----------------
// Col sums over every tile (covers row stats fully on diag tiles); row-side mirror
// added for off-diag tiles. Proven logic from the R0 PASS=0 kernel.
__global__ __launch_bounds__(256, 4)
void sim_stats_k(const __hip_bfloat16* __restrict__ zn,
                 float* __restrict__ rowsum,
                 float* __restrict__ rowsumsq)
{
    __shared__ unsigned short As[2][4096];
    __shared__ unsigned short Bs[2][4096];
    float* cs = (float*)As;        // 512-float scratch overlaid on ring (post-kloop)
    float* cq = cs + 128;
    float* rs = cs + 256;
    float* rq = cs + 384;
    const int tid = threadIdx.x, wave = tid >> 6, lane = tid & 63;
    const int f_l = lane & 15, q_l = lane >> 4;
    int bi, bj;
    decode_tile(blockIdx.x, bi, bj);
    const int R0 = bi * 128, C0 = bj * 128;
    const int wr = wave >> 1, wc = wave & 1;
    f32x4 acc[4][4];
    #pragma unroll
    for (int r = 0; r < 4; ++r)
        #pragma unroll
        for (int c = 0; c < 4; ++c) acc[r][c] = (f32x4){0.f, 0.f, 0.f, 0.f};
    mm_kloop<16>(zn + (size_t)R0 * DIM, DIM, zn + (size_t)C0 * DIM, DIM, As, Bs, acc, wave, lane);

    // safe: every wave passed the final (vmcnt(0)) barrier; all ring reads of As done
    __syncthreads();
    cs[tid] = 0.f; cs[tid + 256] = 0.f;
    __syncthreads();
    #pragma unroll
    for (int c = 0; c < 4; ++c) {
        float s = 0.f, sq = 0.f;
        #pragma unroll
        for (int r = 0; r < 4; ++r) {
            const f32x4 v = acc[r][c];
            #pragma unroll
            for (int u = 0; u < 4; ++u) { s += v[u]; sq += v[u] * v[u]; }
        }
        atomicAdd(&cs[wc * 64 + c * 16 + f_l], s);
        atomicAdd(&cq[wc * 64 + c * 16 + f_l], sq);
    }
    if (bi != bj) {
        #pragma unroll
        for (int r = 0; r < 4; ++r) {
            float s0 = 0, s1 = 0, s2 = 0, s3 = 0, q0 = 0, q1 = 0, q2 = 0, q3 = 0;
            #pragma unroll
            for (int c = 0; c < 4; ++c) {
                const f32x4 v = acc[r][c];
                s0 += v[0]; s1 += v[1]; s2 += v[2]; s3 += v[3];
                q0 += v[0] * v[0]; q1 += v[1] * v[1]; q2 += v[2] * v[2]; q3 += v[3] * v[3];
            }
            #pragma unroll
            for (int off = 1; off < 16; off <<= 1) {
                s0 += __shfl_xor(s0, off); s1 += __shfl_xor(s1, off);
                s2 += __shfl_xor(s2, off); s3 += __shfl_xor(s3, off);
                q0 += __shfl_xor(q0, off); q1 += __shfl_xor(q1, off);
                q2 += __shfl_xor(q2, off); q3 += __shfl_xor(q3, off);
            }
            if (f_l == 0) {
                const int base = wr * 64 + r * 16 + q_l * 4;
                atomicAdd(&rs[base + 0], s0); atomicAdd(&rs[base + 1], s1);
                atomicAdd(&rs[base + 2], s2); atomicAdd(&rs[base + 3], s3);
                atomicAdd(&rq[base + 0], q0); atomicAdd(&rq[base + 1], q1);
                atomicAdd(&rq[base + 2], q2); atomicAdd(&rq[base + 3], q3);
            }
        }
    }
    __syncthreads();
    if (tid < 128) {
        atomicAdd(&rowsum[C0 + tid],   cs[tid]);
        atomicAdd(&rowsumsq[C0 + tid], cq[tid]);
        if (bi != bj) {
            atomicAdd(&rowsum[R0 + tid],   rs[tid]);
            atomicAdd(&rowsumsq[R0 + tid], rq[tid]);
        }
    }
}

// ---------------- stats finalize ----------------
__global__ void finalize_stats_k(const float* __restrict__ rowsum,
                                 const float* __restrict__ rowsumsq,
                                 float* __restrict__ mu_d,
                                 float* __restrict__ inv2s2)
{
    const int j = blockIdx.x * blockDim.x + threadIdx.x;
    if (j < NTOT) {
        const float s  = rowsum[j];
        const float sq = rowsumsq[j];
        const float mean_sim = s * (1.0f / NTOT);
        const float var = (sq - s * mean_sim) * (1.0f / (NTOT - 1));
        mu_d[j]   = 1.0f - mean_sim;
        inv2s2[j] = 1.0f / (2.0f * var);
    }
}

// ---------------- positive pairs (vectorized) ----------------
__global__ __launch_bounds__(256)
void pos_k(const __hip_bfloat16* __restrict__ zn, const int* __restrict__ labels,
           double* __restrict__ pos_acc)
{
    const int wave = threadIdx.x >> 6, lane = threadIdx.x & 63;
    const int pair = blockIdx.x * 4 + wave;
    const bf16x8 va = *(const bf16x8*)(zn + (size_t)pair * DIM + lane * 8);
    const bf16x8 vb = *(const bf16x8*)(zn + (size_t)(pair + BATCH) * DIM + lane * 8);
    float s = 0.f;
    #pragma unroll
    for (int j = 0; j < 8; ++j)
        s += b2f((unsigned short)va[j]) * b2f((unsigned short)vb[j]);
    #pragma unroll
    for (int off = 1; off < 64; off <<= 1) s += __shfl_xor(s, off);
    if (lane == 0 && labels[pair] == labels[pair + BATCH])
        atomicAdd(pos_acc, (double)__expf(s * TEMP_INV));
}

// ---------------- pass 2: triangle GEMM + exp epilogue (R14 proven config) ----------------
__global__ __launch_bounds__(256, 4)
void sim_neg_k(const __hip_bfloat16* __restrict__ zn,
               const int*   __restrict__ labels,
               const float* __restrict__ mu_d,
               const float* __restrict__ inv2s2,
               double* __restrict__ neg_acc)
{
    __shared__ unsigned short As[2][4096];
    __shared__ unsigned short Bs[2][4096];
    float* redbuf = (float*)As[0];   // overlay, safe post-kloop (see sim_stats_k)
    const int tid = threadIdx.x, wave = tid >> 6, lane = tid & 63;
    const int f_l = lane & 15, q_l = lane >> 4;
    int bi, bj;
    decode_tile(blockIdx.x, bi, bj);
    const int R0 = bi * 128, C0 = bj * 128;
    const int wr = wave >> 1, wc = wave & 1;
    f32x4 acc[4][4];
    #pragma unroll
    for (int r = 0; r < 4; ++r)
        #pragma unroll
        for (int c = 0; c < 4; ++c) acc[r][c] = (f32x4){0.f, 0.f, 0.f, 0.f};
    mm_kloop<16>(zn + (size_t)R0 * DIM, DIM, zn + (size_t)C0 * DIM, DIM, As, Bs, acc, wave, lane);

    int labj[4]; float muj[4], isj[4];
    #pragma unroll
    for (int c = 0; c < 4; ++c) {
        const int j = C0 + wc * 64 + c * 16 + f_l;
        labj[c] = labels[j]; muj[c] = mu_d[j]; isj[c] = inv2s2[j];
    }
    float local = 0.f;
    #pragma unroll
    for (int r = 0; r < 4; ++r) {
        const int ib = R0 + wr * 64 + r * 16 + q_l * 4;
        #pragma unroll
        for (int u = 0; u < 4; ++u) {
            const int   li = labels[ib + u];
            const float mi = mu_d[ib + u];
            const float vi = inv2s2[ib + u];
            #pragma unroll
            for (int c = 0; c < 4; ++c) {
                const float s  = acc[r][c][u];
                const float dj = (1.0f - s) - muj[c];
                float e = __expf(s * TEMP_INV + dj * dj * isj[c]);
                if (bi != bj) {
                    const float di = (1.0f - s) - mi;
                    e += __expf(s * TEMP_INV + di * di * vi);
                }
                local += (li != labj[c]) ? e : 0.f;
            }
        }
    }
    #pragma unroll
    for (int off = 1; off < 64; off <<= 1) local += __shfl_xor(local, off);
    __syncthreads();                       // all waves past kloop before LDS reuse
    if (lane == 0) redbuf[wave] = local;
    __syncthreads();
    if (tid == 0)
        atomicAdd(neg_acc, (double)(redbuf[0] + redbuf[1] + redbuf[2] + redbuf[3]));
}

// ---------------- final loss ----------------
__global__ void loss_k(const double* __restrict__ accs, float* __restrict__ out)
{
    const double neg = accs[0], pos = accs[1];
    out[0] = (float)(-log(pos / (pos + neg)));
}

extern "C" void kernel_launch(void* const* d_in, const int* in_sizes, int n_in,
                              void* d_out, int out_size, void* d_ws, size_t ws_size,
                              hipStream_t stream)
{
    const float* z      = (const float*)d_in[0];
    const int*   labels = (const int*)d_in[1];
    float* out = (float*)d_out;

    char* ws = (char*)d_ws;
    __hip_bfloat16* zn = (__hip_bfloat16*)ws;                         // 8 MiB
    char* tail         = ws + ((size_t)8 << 20);
    float*  rowsum   = (float*)tail;                                  // 8192 f
    float*  rowsumsq = rowsum + NTOT;                                 // 8192 f
    double* accs     = (double*)(rowsumsq + NTOT);                    // [0]=neg [1]=pos
    float*  mu_d     = (float*)(accs + 2);                            // 8192 f
    float*  inv2s2   = mu_d + NTOT;                                   // 8192 f

    // zero: rowsum + rowsumsq + accs (contiguous)
    (void)hipMemsetAsync(rowsum, 0, 2 * NTOT * sizeof(float) + 2 * sizeof(double), stream);

    normalize_k<<<NTOT / 4, 256, 0, stream>>>(z, zn);
    sim_stats_k<<<NBLK, 256, 0, stream>>>(zn, rowsum, rowsumsq);
    finalize_stats_k<<<NTOT / 256, 256, 0, stream>>>(rowsum, rowsumsq, mu_d, inv2s2);
    pos_k<<<BATCH / 4, 256, 0, stream>>>(zn, labels, accs + 1);
    sim_neg_k<<<NBLK, 256, 0, stream>>>(zn, labels, mu_d, inv2s2, accs);
    loss_k<<<1, 1, 0, stream>>>(accs, out);
}